// Round 10
// baseline (565.105 us; speedup 1.0000x reference)
//
#include <hip/hip_runtime.h>
#include <stdint.h>

typedef unsigned short u16;
typedef __attribute__((ext_vector_type(8)))  short short8;
typedef __attribute__((ext_vector_type(16))) float f32x16;
typedef __attribute__((ext_vector_type(4)))  float f32x4;

typedef __attribute__((address_space(1))) const void g_void;
typedef __attribute__((address_space(3))) void l_void;

#define SROW 32768            // per-sample tile: 64 rows * 512 B
#define ZOFF 131072           // shared zero row (512 B)
#define SCR  131584           // fp32 DMA scratch (16 KB = 4 samples * 4096 B)
#define LDSB 147968
#define PACK_BYTES (1920ull*1024ull)
#define ZMASK 0x07AB01AA80EAE0FAull

// tap offsets per direction: 0=up, 1=left, 2=right
__device__ const int8_t TAPR[3][5] = {{0,0,1,2,2},{1,2,2,2,3},{1,2,2,2,3}};
__device__ const int8_t TAPC[3][5] = {{0,1,1,1,2},{1,0,1,2,1},{1,1,2,3,3}};

// padded sp -> source pixel (0..63) or -1 (zero); includes the 18 fixup copies
__device__ const int8_t MAP100[100] = {
  59,60,61,62,-1,-1,-1,-1,-1,-1,
  -1, 0, 1, 2, 3,32, 5, 6, 7,-1,
  47, 8, 9,10,11,12,41,14,15,-1,
  -1,16,17,18,19,20,21,50,23,-1,
  63,24,25,26,27,28,29,30,59,-1,
  -1,32,33,34,35,36,37,38,39,-1,
  -1,12,41,42,43,44,45,46,47, 8,
  -1,48,49,50,51,52,53,54,55,16,
  -1,56,57,30,59,60,61,62,63,24,
  -1,-1,-1,-1,-1, 0,-1, 2,-1,32
};

// canonical per-pixel 4-bit hash (same function on write & read side)
__device__ __forceinline__ int hpx(int px) {
  return ((px >> 4) & 3) | (((px >> 1) & 3) << 2);
}

__device__ __forceinline__ u16 f2bf(float f) {
  uint32_t u = __float_as_uint(f);
  return (u16)((u + 0x7FFFu + ((u >> 16) & 1)) >> 16);   // RNE
}

// ---------------- weight pre-pack: exact B-fragment order -------------------
__global__ __launch_bounds__(256) void kag_prep(const float* __restrict__ wU,
                                                const float* __restrict__ wL,
                                                const float* __restrict__ wR,
                                                u16* __restrict__ pack) {
  int tid  = blockIdx.x * 256 + threadIdx.x;
  int l    = tid & 63;
  int frag = tid >> 6;                           // 0..1919
  int d    = frag / 640;
  int rem  = frag - d * 640;
  int t    = rem >> 7;
  int rem2 = rem & 127;
  int cb   = rem2 >> 3;
  int nt   = rem2 & 7;
  const float* w = (d == 0) ? wU : ((d == 1) ? wL : wR);
  int tr = TAPR[d][t], tc = TAPC[d][t];
  int o  = nt * 32 + (l & 31);
  int c0 = cb * 16 + ((l >> 5) << 3);
  const float* wp = w + (size_t)o * 4096 + (size_t)c0 * 16 + tr * 4 + tc;
  union { u16 u[8]; short8 v; } cv;
#pragma unroll
  for (int e = 0; e < 8; ++e) cv.u[e] = f2bf(wp[e * 16]);
  *(short8*)(pack + (size_t)frag * 512 + l * 8) = cv.v;
}

// ------- main: 8 samples/block (2 rounds of 4), DMA-staged pipelined K ------
__global__ __launch_bounds__(768, 3) void kag_main(const float* __restrict__ x,
                                                   const u16* __restrict__ pack,
                                                   const float* __restrict__ bU,
                                                   const float* __restrict__ bL,
                                                   const float* __restrict__ bR,
                                                   float* __restrict__ out) {
  extern __shared__ __align__(16) char lds[];
  const int tid = threadIdx.x;
  const int l   = tid & 63;
  const int w   = tid >> 6;          // 0..11

  // shared zero row (survives both rounds; epilogue tile ends at 131072)
  if (tid < 32) *(short8*)(lds + ZOFF + tid * 16) = (short8)(short)0;

  const int d   = w >> 2;
  const int nt0 = w & 3;
  const int m   = l & 31;
  const int sA  = m >> 4;
  const int pos = m & 15;
  const int i   = pos >> 2, j = pos & 3;
  const int lh  = l >> 5;

  // read-side: tap -> (row via MAP100, hash via hpx)
  int baseT[5], hh5[5];
#pragma unroll
  for (int t = 0; t < 5; ++t) {
    int tr = TAPR[d][t], tc = TAPC[d][t];
    int sp = (2 * i + tr) * 10 + (2 * j + tc);
    int mm = MAP100[sp];
    int bb, hh;
    if (mm >= 0) { bb = sA * SROW + mm * 512; hh = hpx(mm); }
    else         { bb = ZOFF;                 hh = 0; }
    baseT[t] = bb + ((lh ^ (hh & 1)) << 4);
    hh5[t]   = (hh >> 1) << 5;
  }

  const char* pkc = (const char*)pack + (size_t)((d * 640 + nt0) * 1024) + l * 16;

  // convert-phase constants (waves 0..7 active)
  const int cs  = w >> 1, cgg = w & 1;
  const int cpx = ((l & 3) << 4) | (l >> 2);   // lane->pixel permutation
  const int chx = hpx(cpx);
  const float* scrf = (const float*)(lds + SCR);

  short8 wq[3][2];
  short8 aq[2][2];
  f32x16 acc[2][2];

#define DMAISS(CB, BB) {                                                       \
    { const int s_ = w >> 2, i4 = w & 3;                                       \
      const float* gp = x + (size_t)((BB) + s_) * 16384 + (CB) * 1024 + i4 * 256 + l * 4; \
      __builtin_amdgcn_global_load_lds((g_void*)gp,                            \
          (l_void*)(lds + SCR + s_ * 4096 + i4 * 1024), 16, 0, 0); }           \
    if (w < 4) {                                                               \
      const float* gp = x + (size_t)((BB) + 3) * 16384 + (CB) * 1024 + w * 256 + l * 4; \
      __builtin_amdgcn_global_load_lds((g_void*)gp,                            \
          (l_void*)(lds + SCR + 3 * 4096 + w * 1024), 16, 0, 0); }             \
    __builtin_amdgcn_sched_barrier(0); }

#define CONVERT(CB) if (w < 8) {                                               \
    const float* sp_ = scrf + cs * 1024 + cgg * 512 + cpx;                     \
    union { u16 u[8]; short8 v; } cv;                                          \
    cv.u[0]=f2bf(sp_[0]);   cv.u[1]=f2bf(sp_[64]);  cv.u[2]=f2bf(sp_[128]);    \
    cv.u[3]=f2bf(sp_[192]); cv.u[4]=f2bf(sp_[256]); cv.u[5]=f2bf(sp_[320]);    \
    cv.u[6]=f2bf(sp_[384]); cv.u[7]=f2bf(sp_[448]);                            \
    const int g_ = 2 * (CB) + cgg;                                             \
    *(short8*)(lds + cs * SROW + cpx * 512 + ((g_ ^ chx) << 4)) = cv.v; }

#define PRIMEA(Q) { const int off_ = ((Q) << 5) ^ hh5[0];                      \
    aq[(Q)&1][0] = *(const short8*)(lds + baseT[0] + off_);                    \
    aq[(Q)&1][1] = *(const short8*)(lds + baseT[0] + 2 * SROW + off_); }

#define KSTAGE(S) {                                                            \
    if ((S) + 2 < 80) {                                                        \
      const int s3 = (S) + 2, cb3 = s3 / 5, t3 = s3 - cb3 * 5;                 \
      const size_t bo = (size_t)(t3 * 16 + cb3) * 8192;                        \
      wq[s3 % 3][0] = *(const short8*)(pkc + bo);                              \
      wq[s3 % 3][1] = *(const short8*)(pkc + bo + 4096);                       \
    }                                                                          \
    if (((S) + 1) % 5 != 0) {                                                  \
      const int s1 = (S) + 1, cb1 = s1 / 5, t1 = s1 - cb1 * 5;                 \
      const int off_ = (cb1 << 5) ^ hh5[t1];                                   \
      aq[s1 & 1][0] = *(const short8*)(lds + baseT[t1] + off_);                \
      aq[s1 & 1][1] = *(const short8*)(lds + baseT[t1] + 2 * SROW + off_);     \
    }                                                                          \
    acc[0][0] = __builtin_amdgcn_mfma_f32_32x32x16_bf16(aq[(S)&1][0], wq[(S)%3][0], acc[0][0], 0, 0, 0); \
    acc[0][1] = __builtin_amdgcn_mfma_f32_32x32x16_bf16(aq[(S)&1][0], wq[(S)%3][1], acc[0][1], 0, 0, 0); \
    acc[1][0] = __builtin_amdgcn_mfma_f32_32x32x16_bf16(aq[(S)&1][1], wq[(S)%3][0], acc[1][0], 0, 0, 0); \
    acc[1][1] = __builtin_amdgcn_mfma_f32_32x32x16_bf16(aq[(S)&1][1], wq[(S)%3][1], acc[1][1], 0, 0, 0); }

#pragma unroll 1
  for (int rnd = 0; rnd < 2; ++rnd) {
    const int b0 = blockIdx.x * 8 + rnd * 4;

    if (rnd == 0) DMAISS(0, b0)

    // prime B stages 0,1
#pragma unroll
    for (int s = 0; s < 2; ++s) {
      const size_t bo = (size_t)(s * 16) * 8192;
      wq[s][0] = *(const short8*)(pkc + bo);
      wq[s][1] = *(const short8*)(pkc + bo + 4096);
    }
#pragma unroll
    for (int p = 0; p < 2; ++p)
#pragma unroll
      for (int h = 0; h < 2; ++h)
#pragma unroll
        for (int r2 = 0; r2 < 16; ++r2) acc[p][h][r2] = 0.f;

    __syncthreads();      // chunk 0 landed
    CONVERT(0)
    __syncthreads();      // tile granules 0,1 visible
    PRIMEA(0)

#pragma unroll
    for (int q = 0; q < 16; ++q) {
      if (q < 15) DMAISS(q + 1, b0)
      KSTAGE(5*q+0) KSTAGE(5*q+1) KSTAGE(5*q+2) KSTAGE(5*q+3) KSTAGE(5*q+4)
      if (q < 15) {
        __syncthreads();      // DMA(q+1) landed; convert may read scratch
        CONVERT(q + 1)
        __syncthreads();      // converted granules visible to all waves
        PRIMEA(q + 1)
      }
    }

    if (rnd == 0) DMAISS(0, b0 + 4)   // round-2 chunk0 rides into the epilogue
    __syncthreads();                  // K-phase reads done before tile overwrite

    // ---- epilogue: 2 rounds of sample-pairs via swizzled tile ----
    const float* bp = (d == 0) ? bU : ((d == 1) ? bL : bR);
    const int ol = l & 31;
    const int o0 = nt0 * 32 + ol;
    const int o1 = o0 + 128;
    const float bias0 = bp[o0];
    const float bias1 = bp[o1];
    const int lh4 = lh * 4;
    float* ldsf = (float*)lds;

#pragma unroll
    for (int r = 0; r < 2; ++r) {
#pragma unroll
      for (int r2 = 0; r2 < 16; ++r2) {
        int row = (r2 & 3) + 8 * (r2 >> 2) + lh4;    // 0..31
        int sq  = row >> 4;
        int p2  = row & 15;
        int i2 = p2 >> 2, j2 = p2 & 3;
        int outp = 16 * i2 + 2 * j2 + ((d > 0) ? 8 : 0) + (d >> 1);
        ldsf[(sq * 256 + o0) * 64 + (outp ^ ((o0 & 15) << 2))] = acc[r][0][r2] + bias0;
        ldsf[(sq * 256 + o1) * 64 + (outp ^ ((o1 & 15) << 2))] = acc[r][1][r2] + bias1;
      }
      __syncthreads();
      for (int cc = tid; cc < 8192; cc += 768) {
        int sq = cc >> 12, rem = cc & 4095;
        int o  = rem >> 4, pb = rem & 15;
        f32x4 v = *(f32x4*)(ldsf + (sq * 256 + o) * 64 + ((pb ^ (o & 15)) << 2));
#pragma unroll
        for (int kk = 0; kk < 4; ++kk)
          if ((ZMASK >> (pb * 4 + kk)) & 1ull) v[kk] = 0.f;
        __builtin_nontemporal_store(v,
            (f32x4*)(out + (((size_t)(b0 + 2 * r + sq) * 256 + o) << 6) + pb * 4));
      }
      __syncthreads();
    }
  }
#undef DMAISS
#undef CONVERT
#undef PRIMEA
#undef KSTAGE
}

// ---------------- slow fp32 fallback (only if ws too small) -----------------
__global__ __launch_bounds__(256) void kag_fallback(const float* __restrict__ x,
    const float* __restrict__ wU, const float* __restrict__ bU,
    const float* __restrict__ wL, const float* __restrict__ bL,
    const float* __restrict__ wR, const float* __restrict__ bR,
    float* __restrict__ out) {
  long long tid = (long long)blockIdx.x * 256 + threadIdx.x;
  if (tid >= (long long)2048 * 256 * 48) return;
  int pd = (int)(tid % 48);
  long long rem = tid / 48;
  int o = (int)(rem % 256);
  int b = (int)(rem / 256);
  int d = pd >> 4, pos = pd & 15;
  int i = pos >> 2, j = pos & 3;
  int outp = 16 * i + 2 * j + ((d > 0) ? 8 : 0) + (d >> 1);
  if ((ZMASK >> outp) & 1ull) return;
  const float* ws = (d == 0) ? wU : ((d == 1) ? wL : wR);
  const float* bs = (d == 0) ? bU : ((d == 1) ? bL : bR);
  float acc = bs[o];
  int spv[5], wofs[5];
#pragma unroll
  for (int t = 0; t < 5; ++t) {
    int tr = TAPR[d][t], tc = TAPC[d][t];
    spv[t]  = (2 * i + tr) * 10 + (2 * j + tc);
    wofs[t] = tr * 4 + tc;
  }
  for (int c = 0; c < 256; ++c) {
    const float* xc = x + ((size_t)b * 256 + c) * 64;
    const float* wc = ws + (size_t)o * 4096 + (size_t)c * 16;
#pragma unroll
    for (int t = 0; t < 5; ++t) {
      int px = MAP100[spv[t]];
      if (px >= 0) acc += xc[px] * wc[wofs[t]];
    }
  }
  out[((size_t)b * 256 + o) * 64 + outp] = acc;
}

extern "C" void kernel_launch(void* const* d_in, const int* in_sizes, int n_in,
                              void* d_out, int out_size, void* d_ws, size_t ws_size,
                              hipStream_t stream) {
  const float* x  = (const float*)d_in[0];
  const float* wU = (const float*)d_in[1];
  const float* bU = (const float*)d_in[2];
  const float* wL = (const float*)d_in[3];
  const float* bL = (const float*)d_in[4];
  const float* wR = (const float*)d_in[5];
  const float* bR = (const float*)d_in[6];
  float* out = (float*)d_out;

  if (ws_size >= PACK_BYTES) {
    u16* pack = (u16*)d_ws;
    kag_prep<<<480, 256, 0, stream>>>(wU, wL, wR, pack);
    hipFuncSetAttribute(reinterpret_cast<const void*>(kag_main),
                        hipFuncAttributeMaxDynamicSharedMemorySize, LDSB);
    kag_main<<<256, 768, LDSB, stream>>>(x, pack, bU, bL, bR, out);
  } else {
    hipMemsetAsync(d_out, 0, (size_t)out_size * 4, stream);
    kag_fallback<<<98304, 256, 0, stream>>>(x, wU, bU, wL, bL, wR, bR, out);
  }
}